// Round 14
// baseline (164.837 us; speedup 1.0000x reference)
//
#include <hip/hip_runtime.h>

// Problem constants (fixed by the reference).
constexpr int IN_CH = 4;
constexpr int KS    = 40;
constexpr int L_IN  = 8192;
constexpr int L_OUT = L_IN - KS + 1;   // 8153
constexpr int NF    = 600;
constexpr int BATCH = 32;

typedef float floatx4  __attribute__((ext_vector_type(4)));                 // 16B-aligned (stores)
typedef float floatx4u __attribute__((ext_vector_type(4), aligned(4)));     // 4B-aligned (reads)

// ---- Kernel 1: taps. rec[k] = float4{ off0, off1, w0, w1 }, off = c*L_IN + p ----
__global__ void tap_kernel(const float* __restrict__ w, float* __restrict__ ws) {
    const int k = blockIdx.x * 256 + threadIdx.x;
    if (k >= NF) return;
    const float* wk = w + (size_t)k * IN_CH * KS;
    int n = 0; int off[2] = {0, 0}; float val[2] = {0.f, 0.f};
    for (int i = 0; i < IN_CH * KS; ++i) {
        const float v = wk[i];
        if (v != 0.0f && n < 2) { off[n] = (i / KS) * L_IN + (i % KS); val[n] = v; ++n; }
    }
    if (n == 1) { off[1] = off[0]; val[1] = 0.0f; }   // defensive
    float4 r;
    r.x = __int_as_float(off[0]);
    r.y = __int_as_float(off[1]);
    r.z = val[0];
    r.w = val[1];
    *reinterpret_cast<float4*>(ws + (size_t)k * 4) = r;
}

// ---- Kernel 2: one block per output row (19200 blocks = max store parallelism,
// the proven first-order lever). Reads straight from x via unaligned dwordx4
// (x = 4 MB, L2-resident; proven R13). R14 single-variable change vs R13:
// PLAIN stores instead of nontemporal (theory: L2 write-back aggregation emits
// long address-ordered bursts to HBM like fillBuffer's 6.8 TB/s, vs NT's
// ~2048 interleaved 1KB streams draining at 4.4 TB/s).
__global__ __launch_bounds__(256) void fdc_row(const float* __restrict__ x,
                                               const float* __restrict__ ws,
                                               float* __restrict__ out) {
    const int bid = blockIdx.x;
    const int row = (bid & 7) * (NF * BATCH / 8) + (bid >> 3);   // bijective XCD swizzle
    const int b   = row / NF;
    const int k   = row - b * NF;

    const float4 r  = *reinterpret_cast<const float4*>(ws + (size_t)k * 4);
    const float* xb = x + (size_t)b * IN_CH * L_IN;
    const float* x0 = xb + __float_as_int(r.x);
    const float* x1 = xb + __float_as_int(r.y);
    const float  w0 = r.z, w1 = r.w;

    const size_t e0   = (size_t)row * L_OUT;
    float*       orow = out + e0;
    const int    a    = (int)((0u - (unsigned)e0) & 15u);  // head elems to 64B boundary
    const int    n4   = (L_OUT - a) >> 2;                  // aligned float4s (~2036)
    const int    tail = L_OUT - a - (n4 << 2);             // <= 3

#pragma unroll 2
    for (int t = threadIdx.x; t < n4; t += 256) {
        const int l = a + t * 4;
        const floatx4u v0 = *reinterpret_cast<const floatx4u*>(x0 + l);
        const floatx4u v1 = *reinterpret_cast<const floatx4u*>(x1 + l);
        floatx4 v;
        v.x = w0 * v0.x + w1 * v1.x;
        v.y = w0 * v0.y + w1 * v1.y;
        v.z = w0 * v0.z + w1 * v1.z;
        v.w = w0 * v0.w + w1 * v1.w;
        *reinterpret_cast<floatx4*>(orow + l) = v;   // plain store (was NT)
    }

    // head [0,a) + tail [a+4*n4, L_OUT): <= 18 scalars, once per block
    if (threadIdx.x < 24) {
        int elem = -1;
        if ((int)threadIdx.x < a) {
            elem = (int)threadIdx.x;
        } else {
            const int rr = (int)threadIdx.x - a;
            if (rr < tail) elem = a + (n4 << 2) + rr;
        }
        if (elem >= 0) orow[elem] = w0 * x0[elem] + w1 * x1[elem];
    }
}

extern "C" void kernel_launch(void* const* d_in, const int* in_sizes, int n_in,
                              void* d_out, int out_size, void* d_ws, size_t ws_size,
                              hipStream_t stream) {
    const float* x  = (const float*)d_in[0];   // [32, 4, 8192] fp32
    const float* w  = (const float*)d_in[1];   // [600, 4, 40]  fp32
    float*       o  = (float*)d_out;           // [32, 600, 8153] fp32
    float*       ws = (float*)d_ws;            // 600 * float4 tap table (9.6 KB)

    tap_kernel<<<(NF + 255) / 256, 256, 0, stream>>>(w, ws);
    fdc_row<<<NF * BATCH, 256, 0, stream>>>(x, ws, o);   // 19200 blocks, 1 row each
}

// Round 15
// 124.839 us; speedup vs baseline: 1.3204x; 1.3204x over previous
//
#include <hip/hip_runtime.h>

// Problem constants (fixed by the reference).
constexpr int IN_CH = 4;
constexpr int KS    = 40;
constexpr int L_IN  = 8192;
constexpr int L_OUT = L_IN - KS + 1;   // 8153
constexpr int NF    = 600;
constexpr int BATCH = 32;

typedef float floatx4  __attribute__((ext_vector_type(4)));                 // 16B-aligned (stores)
typedef float floatx4u __attribute__((ext_vector_type(4), aligned(4)));     // 4B-aligned (reads)

// One block per output row (19200 blocks = max store parallelism, the proven
// first-order lever). Reads straight from x via unaligned dwordx4 (x = 4 MB,
// L2-resident; R13). NT stores + 64B-aligned bursts with head/tail peel
// (R6/R9/R14: NT worth -16us). R15 single change vs R13: tap extraction fused
// into this kernel via wave ballot (no tap_kernel dispatch, no graph dep).
// Each filter has exactly 2 nonzero taps (reference weight builder), found as
// first/last set bit of ballot masks over the 160 weights -- deterministic,
// same row-major order as the old sequential scan.
__global__ __launch_bounds__(256) void fdc_row(const float* __restrict__ x,
                                               const float* __restrict__ w,
                                               float* __restrict__ out) {
    const int bid = blockIdx.x;
    const int row = (bid & 7) * (NF * BATCH / 8) + (bid >> 3);   // bijective XCD swizzle
    const int b   = row / NF;
    const int k   = row - b * NF;

    // ---- per-block tap extraction (all waves redundant; uniform result) ----
    const float* wk  = w + (size_t)k * IN_CH * KS;   // 160 floats
    const int    lane = threadIdx.x & 63;
    const float  a0 = wk[lane];
    const float  a1 = wk[lane + 64];
    const float  a2 = (lane < 32) ? wk[lane + 128] : 0.0f;   // guard k=599 OOB
    const unsigned long long m0 = __ballot(a0 != 0.0f);
    const unsigned long long m1 = __ballot(a1 != 0.0f);
    const unsigned long long m2 = __ballot(a2 != 0.0f);
    int i0, i1;
    if (m0)      i0 = __builtin_ctzll(m0);
    else if (m1) i0 = 64 + __builtin_ctzll(m1);
    else         i0 = 128 + __builtin_ctzll(m2);
    if (m2)      i1 = 128 + 63 - __builtin_clzll(m2);
    else if (m1) i1 = 64 + 63 - __builtin_clzll(m1);
    else         i1 = 63 - __builtin_clzll(m0);
    const float w0 = wk[i0];                          // uniform scalar loads
    const float w1 = wk[i1];

    const float* xb = x + (size_t)b * IN_CH * L_IN;
    const float* x0 = xb + (i0 / KS) * L_IN + (i0 % KS);
    const float* x1 = xb + (i1 / KS) * L_IN + (i1 % KS);

    const size_t e0   = (size_t)row * L_OUT;
    float*       orow = out + e0;
    const int    a    = (int)((0u - (unsigned)e0) & 15u);  // head elems to 64B boundary
    const int    n4   = (L_OUT - a) >> 2;                  // aligned float4s (~2036)
    const int    tail = L_OUT - a - (n4 << 2);             // <= 3

#pragma unroll 2
    for (int t = threadIdx.x; t < n4; t += 256) {
        const int l = a + t * 4;
        const floatx4u v0 = *reinterpret_cast<const floatx4u*>(x0 + l);
        const floatx4u v1 = *reinterpret_cast<const floatx4u*>(x1 + l);
        floatx4 v;
        v.x = w0 * v0.x + w1 * v1.x;
        v.y = w0 * v0.y + w1 * v1.y;
        v.z = w0 * v0.z + w1 * v1.z;
        v.w = w0 * v0.w + w1 * v1.w;
        __builtin_nontemporal_store(v, reinterpret_cast<floatx4*>(orow + l));
    }

    // head [0,a) + tail [a+4*n4, L_OUT): <= 18 scalars, once per block
    if (threadIdx.x < 24) {
        int elem = -1;
        if ((int)threadIdx.x < a) {
            elem = (int)threadIdx.x;
        } else {
            const int rr = (int)threadIdx.x - a;
            if (rr < tail) elem = a + (n4 << 2) + rr;
        }
        if (elem >= 0) orow[elem] = w0 * x0[elem] + w1 * x1[elem];
    }
}

extern "C" void kernel_launch(void* const* d_in, const int* in_sizes, int n_in,
                              void* d_out, int out_size, void* d_ws, size_t ws_size,
                              hipStream_t stream) {
    const float* x = (const float*)d_in[0];   // [32, 4, 8192] fp32
    const float* w = (const float*)d_in[1];   // [600, 4, 40]  fp32
    float*       o = (float*)d_out;           // [32, 600, 8153] fp32
    (void)d_ws; (void)ws_size;

    fdc_row<<<NF * BATCH, 256, 0, stream>>>(x, w, o);   // single dispatch
}